// Round 19
// baseline (252.156 us; speedup 1.0000x reference)
//
#include <hip/hip_runtime.h>
#include <hip/hip_fp16.h>
#include <math.h>

#define NNODES 50000
#define DIM 128
#define NEDGES 640000
#define NPART 8         // one dst-partition per XCD
#define PART_SZ 6250    // 50000 / 8
#define ACH2 128        // partA chunks (640000/128 = 5000 exact)
#define APER2 5000
#define RCAP 768        // region cap: binom(5000,1/8) mean 625, sd 23 (+6sd)
#define CG 16           // chunk-groups for hist/place
#define CPG 8           // chunks per group (16*8 = 128)
#define WCAPP 84000     // per-partition slot window (mean 80000, sd 265, +15sd)
#define ESLOTS (NPART * WCAPP)   // 672000 slots per etype
#define STRIP 782       // scan strip size (8*782 = 6256 >= 6250)
#define NSTRIP 8

typedef _Float16 half8 __attribute__((ext_vector_type(8)));
typedef _Float16 half4v __attribute__((ext_vector_type(4)));
typedef _Float16 half2v __attribute__((ext_vector_type(2)));
typedef float f32x4 __attribute__((ext_vector_type(4)));

struct H2x4 { half2v a, b, c, d; };

// ---------------------------------------------------------------------------
// partA (standalone, lightweight): radix-compact edges by dst-partition.
// ---------------------------------------------------------------------------
struct PartAArgs {
    const int* src[4];
    const int* dst[4];
    unsigned int* region;   // [4][ACH2][8][RCAP]
    int* cntA;              // [4][ACH2][8]
};

__global__ __launch_bounds__(256) void partA_kernel(PartAArgs A)
{
    const int et = blockIdx.y;
    const int chunk = blockIdx.x;
    const int wave = threadIdx.x >> 6;
    const int lane = threadIdx.x & 63;

    __shared__ int cur[8];
    if (threadIdx.x < 8) cur[threadIdx.x] = 0;
    __syncthreads();

    const int* __restrict__ ds = A.dst[et];
    const int* __restrict__ ss = A.src[et];
    unsigned int* __restrict__ reg =
        A.region + (size_t)(et * ACH2 + chunk) * 8 * RCAP;

    const int wlo = chunk * APER2 + wave * (APER2 / 4);   // 1250 per wave
    const int whi = wlo + (APER2 / 4);
    const unsigned long long ltm = (1ULL << lane) - 1ULL;

    const int iters = (APER2 / 4 + 63) / 64;              // 20
    for (int it = 0; it < iters; ++it) {
        const int e = wlo + it * 64 + lane;
        const bool act = e < whi;
        int d = 0, s = 0;
        if (act) { d = ds[e]; s = ss[e]; }
        const int pe = act ? (d / PART_SZ) : 8;
        const unsigned int pack =
            ((unsigned int)s << 13) | (unsigned int)(d - pe * PART_SZ);
        #pragma unroll
        for (int p = 0; p < 8; ++p) {
            const unsigned long long m = __ballot(pe == p);
            if (m == 0ULL) continue;
            const int leader = __builtin_ctzll(m);
            const int rank = __popcll(m & ltm);
            int base = 0;
            if (lane == leader) base = atomicAdd(&cur[p], __popcll(m));
            base = __shfl(base, leader);
            if (pe == p) {
                const int pos = base + rank;
                if (pos < RCAP) reg[p * RCAP + pos] = pack;
            }
        }
    }
    __syncthreads();
    if (threadIdx.x < 8)
        A.cntA[(et * ACH2 + chunk) * 8 + threadIdx.x] = cur[threadIdx.x];
}

// ---------------------------------------------------------------------------
// proj2: grid (391, ntype, w3) -- ONE weight matrix per block, single
// stage, no serial W-loop. 512 thr, 128 rows/block, 32 KB LDS.
//   w3==0: ht table -> raw f16 row + aux = 1/||row||
//   w3>0:  hr table -> row/||row|| f16 + aux = ||row||
// ---------------------------------------------------------------------------
struct Proj2Args {
    const float* feat[2];
    const float* W[2][3];
    const float* bias[2];
    _Float16* out[2][3];
    float* aux[2][3];
};

__global__ __launch_bounds__(512) void proj2_kernel(Proj2Args args, int n)
{
    const int p = blockIdx.y;
    const int w3 = blockIdx.z;
    const float* __restrict__ feat = args.feat[p];

    __shared__ _Float16 wlds[DIM * DIM];    // 32 KB
    char* wb = (char*)wlds;

    // ---- stage W[p][w3] (f32 [o][k]) -> LDS f16, XOR-swizzled ----
    {
        const float* __restrict__ W = args.W[p][w3];
        const int t = threadIdx.x;
        #pragma unroll
        for (int j = 0; j < 8; ++j) {
            const int idx4 = j * 512 + t;
            const float4 v = *(const float4*)(W + (size_t)idx4 * 4);
            const int o = idx4 >> 5;
            const int k = (idx4 * 4) & 127;
            half4v h;
            h[0] = (_Float16)v.x; h[1] = (_Float16)v.y;
            h[2] = (_Float16)v.z; h[3] = (_Float16)v.w;
            const int addr = (o * 256 + k * 2) ^ ((o & 7) << 4);
            *(half4v*)(wb + addr) = h;
        }
    }

    const int wave = threadIdx.x >> 6;
    const int lane = threadIdx.x & 63;
    const int l15 = lane & 15;
    const int grp = lane >> 4;
    const int rbase = blockIdx.x * 128 + wave * 16;

    half8 afrag[4];
    const int arow = rbase + l15;
    const bool arow_ok = arow < n;
    #pragma unroll
    for (int kt = 0; kt < 4; ++kt) {
        float av[8];
        if (arow_ok) {
            const float* src = feat + (size_t)arow * DIM + kt * 32 + grp * 8;
            const float4 v0 = *(const float4*)(src);
            const float4 v1 = *(const float4*)(src + 4);
            av[0] = v0.x; av[1] = v0.y; av[2] = v0.z; av[3] = v0.w;
            av[4] = v1.x; av[5] = v1.y; av[6] = v1.z; av[7] = v1.w;
        } else {
            #pragma unroll
            for (int j = 0; j < 8; ++j) av[j] = 0.f;
        }
        #pragma unroll
        for (int j = 0; j < 8; ++j) afrag[kt][j] = (_Float16)av[j];
    }

    __syncthreads();

    const int crow0 = rbase + grp * 4;
    _Float16* __restrict__ out = args.out[p][w3];
    float* __restrict__ aux = args.aux[p][w3];

    f32x4 accs[8];
    #pragma unroll
    for (int ct = 0; ct < 8; ++ct) {
        f32x4 acc = {0.f, 0.f, 0.f, 0.f};
        #pragma unroll
        for (int kt = 0; kt < 4; ++kt) {
            const int o = ct * 16 + l15;
            const int addr = (o * 256 + kt * 64 + grp * 16) ^ ((o & 7) << 4);
            const half8 b = *(const half8*)(wb + addr);
            acc = __builtin_amdgcn_mfma_f32_16x16x32_f16(afrag[kt], b, acc, 0, 0, 0);
        }
        if (w3 == 0) {
            const float bb = args.bias[p][ct * 16 + l15];
            acc[0] += bb; acc[1] += bb; acc[2] += bb; acc[3] += bb;
        }
        accs[ct] = acc;
    }

    float nsq[4] = {0.f, 0.f, 0.f, 0.f};
    #pragma unroll
    for (int ct = 0; ct < 8; ++ct) {
        #pragma unroll
        for (int i = 0; i < 4; ++i)
            nsq[i] = fmaf(accs[ct][i], accs[ct][i], nsq[i]);
    }
    #pragma unroll
    for (int i = 0; i < 4; ++i) {
        float v = nsq[i];
        v += __shfl_xor(v, 1); v += __shfl_xor(v, 2);
        v += __shfl_xor(v, 4); v += __shfl_xor(v, 8);
        nsq[i] = fmaxf(v, 1e-30f);
    }

    if (w3 == 0) {
        #pragma unroll
        for (int ct = 0; ct < 8; ++ct)
            #pragma unroll
            for (int i = 0; i < 4; ++i) {
                const int row = crow0 + i;
                if (row < n)
                    out[(size_t)row * DIM + ct * 16 + l15] = (_Float16)accs[ct][i];
            }
        if (l15 == 0) {
            #pragma unroll
            for (int i = 0; i < 4; ++i) {
                const int row = crow0 + i;
                if (row < n) aux[row] = 1.0f / sqrtf(nsq[i]);
            }
        }
    } else {
        float rn[4];
        #pragma unroll
        for (int i = 0; i < 4; ++i) rn[i] = 1.0f / sqrtf(nsq[i]);
        #pragma unroll
        for (int ct = 0; ct < 8; ++ct)
            #pragma unroll
            for (int i = 0; i < 4; ++i) {
                const int row = crow0 + i;
                if (row < n)
                    out[(size_t)row * DIM + ct * 16 + l15] =
                        (_Float16)(accs[ct][i] * rn[i]);
            }
        if (l15 == 0) {
            #pragma unroll
            for (int i = 0; i < 4; ++i) {
                const int row = crow0 + i;
                if (row < n) aux[row] = sqrtf(nsq[i]);
            }
        }
    }
}

// ---------------------------------------------------------------------------
// sort chain (u8 metadata): hist -> scan -> place
// ---------------------------------------------------------------------------
struct SortArgs {
    const unsigned int* region;
    const int* cntA;
    unsigned char* cntH;    // [4][CG][8][PART_SZ]
    int* stripT;            // [4][CG][8][NSTRIP]
    unsigned char* curRel;  // [4][CG][8][PART_SZ]
    unsigned int* offp;     // [4][NNODES]  (abs_start<<8)|deg
    unsigned short* slots;  // [4][ESLOTS]
};

__global__ __launch_bounds__(256) void hist_kernel(SortArgs A)
{
    const int et = blockIdx.y;
    const int cg = blockIdx.x >> 3;
    const int part = blockIdx.x & 7;
    const int tid = threadIdx.x;

    __shared__ int cnt[PART_SZ];          // 25 KB
    for (int i = tid; i < PART_SZ; i += 256) cnt[i] = 0;
    __syncthreads();

    #pragma unroll
    for (int k = 0; k < CPG; ++k) {
        const int c = cg * CPG + k;
        int m = A.cntA[(et * ACH2 + c) * 8 + part];
        if (m > RCAP) m = RCAP;
        const unsigned int* __restrict__ r =
            A.region + ((size_t)(et * ACH2 + c) * 8 + part) * RCAP;
        for (int i = tid; i < m; i += 256)
            atomicAdd(&cnt[r[i] & 8191u], 1);
    }
    __syncthreads();

    unsigned char* __restrict__ out =
        A.cntH + ((size_t)(et * CG + cg) * 8 + part) * PART_SZ;
    for (int i = tid; i < PART_SZ; i += 256)
        out[i] = (unsigned char)(cnt[i] < 255 ? cnt[i] : 255);

    if (tid < 64) {
        for (int s = 0; s < NSTRIP; ++s) {
            const int lo = s * STRIP;
            const int sz = (lo + STRIP < PART_SZ) ? STRIP : (PART_SZ - lo);
            int partial = 0;
            for (int i = tid; i < sz; i += 64) partial += cnt[lo + i];
            partial += __shfl_xor(partial, 1);
            partial += __shfl_xor(partial, 2);
            partial += __shfl_xor(partial, 4);
            partial += __shfl_xor(partial, 8);
            partial += __shfl_xor(partial, 16);
            partial += __shfl_xor(partial, 32);
            if (tid == 0)
                A.stripT[((et * CG + cg) * 8 + part) * NSTRIP + s] = partial;
        }
    }
}

__global__ __launch_bounds__(256) void scan_kernel(SortArgs A)
{
    const int et = blockIdx.y;
    const int part = blockIdx.x & 7;
    const int strip = blockIdx.x >> 3;
    const int t = threadIdx.x;
    const int nlo = strip * STRIP;
    const int nsz = (nlo + STRIP < PART_SZ) ? STRIP : (PART_SZ - nlo);

    __shared__ int tile[CG][STRIP];       // 50 KB
    __shared__ int red[2][256];
    __shared__ int sbase;

    const size_t base0 = ((size_t)(et * CG) * 8 + part) * PART_SZ;
    const size_t cgs = (size_t)8 * PART_SZ;

    for (int cg = 0; cg < CG; ++cg)
        for (int i = t; i < nsz; i += 256)
            tile[cg][i] = (int)A.cntH[base0 + cg * cgs + nlo + i];

    {
        int partial = 0;
        for (int idx = t; idx < CG * NSTRIP; idx += 256) {
            const int cg = idx >> 3;
            const int s = idx & 7;
            if (s < strip)
                partial += A.stripT[((et * CG + cg) * 8 + part) * NSTRIP + s];
        }
        red[0][t] = partial;
        __syncthreads();
        for (int d = 128; d > 0; d >>= 1) {
            if (t < d) red[0][t] += red[0][t + d];
            __syncthreads();
        }
        if (t == 0) sbase = red[0][0];
        __syncthreads();
    }

    int s = 0;
    #pragma unroll
    for (int k = 0; k < 4; ++k) {
        const int idx = t * 4 + k;
        if (idx < nsz) {
            int deg = 0;
            for (int cg = 0; cg < CG; ++cg) deg += tile[cg][idx];
            s += deg;
        }
    }
    red[0][t] = s;
    __syncthreads();
    int pp = 0;
    for (int d = 1; d < 256; d <<= 1) {
        int v = red[pp][t];
        if (t >= d) v += red[pp][t - d];
        red[pp ^ 1][t] = v;
        pp ^= 1;
        __syncthreads();
    }
    int run = part * WCAPP + sbase + (t == 0 ? 0 : red[pp][t - 1]);

    unsigned int* __restrict__ offe = A.offp + et * NNODES + part * PART_SZ + nlo;
    #pragma unroll
    for (int k = 0; k < 4; ++k) {
        const int idx = t * 4 + k;
        if (idx < nsz) {
            const int nb = run;
            int b = run;
            for (int cg = 0; cg < CG; ++cg) {
                A.curRel[base0 + cg * cgs + nlo + idx] = (unsigned char)(b - nb);
                b += tile[cg][idx];
            }
            const int deg = b - nb;
            offe[idx] = ((unsigned int)nb << 8) |
                        (unsigned int)(deg < 255 ? deg : 255);
            run = b;
        }
    }
}

__global__ __launch_bounds__(256) void place_kernel(SortArgs A)
{
    const int et = blockIdx.y;
    const int cg = blockIdx.x >> 3;
    const int part = blockIdx.x & 7;
    const int tid = threadIdx.x;

    __shared__ int cur[PART_SZ];          // 25 KB
    const unsigned char* __restrict__ crel =
        A.curRel + ((size_t)(et * CG + cg) * 8 + part) * PART_SZ;
    const unsigned int* __restrict__ offe =
        A.offp + et * NNODES + part * PART_SZ;
    for (int i = tid; i < PART_SZ; i += 256)
        cur[i] = (int)(offe[i] >> 8) + (int)crel[i];
    __syncthreads();

    unsigned short* __restrict__ sl = A.slots + (size_t)et * ESLOTS;

    #pragma unroll
    for (int k = 0; k < CPG; ++k) {
        const int c = cg * CPG + k;
        int m = A.cntA[(et * ACH2 + c) * 8 + part];
        if (m > RCAP) m = RCAP;
        const unsigned int* __restrict__ r =
            A.region + ((size_t)(et * ACH2 + c) * 8 + part) * RCAP;
        for (int i = tid; i < m; i += 256) {
            const unsigned int pk = r[i];
            const int dl = (int)(pk & 8191u);
            const int pos = atomicAdd(&cur[dl], 1);
            if (pos < ESLOTS) sl[pos] = (unsigned short)(pk >> 13);
        }
    }
}

// ---------------------------------------------------------------------------
// aggregate (r15 inner form; one dispatch per half for top-5 visibility,
// r17-proven neutral): wave per dst node, 16 lanes/edge, fdot2, f16 packed
// accumulate, 1-deep prefetch, XCD-aligned.
// ---------------------------------------------------------------------------
struct AggHalf {
    const _Float16* ht; const float* invnt;
    const _Float16* hrA; const float* nrmA;
    const unsigned int* offA; const unsigned short* slotsA;
    const _Float16* hrB; const float* nrmB;
    const unsigned int* offB; const unsigned short* slotsB;
    float* out;
};

__device__ __forceinline__ float dot16(half8 hv, half8 tv)
{
    float p = 0.f;
#if __has_builtin(__builtin_amdgcn_fdot2)
    const H2x4 hu = __builtin_bit_cast(H2x4, hv);
    const H2x4 tu = __builtin_bit_cast(H2x4, tv);
    p = __builtin_amdgcn_fdot2(hu.a, tu.a, p, false);
    p = __builtin_amdgcn_fdot2(hu.b, tu.b, p, false);
    p = __builtin_amdgcn_fdot2(hu.c, tu.c, p, false);
    p = __builtin_amdgcn_fdot2(hu.d, tu.d, p, false);
#else
    #pragma unroll
    for (int j = 0; j < 8; ++j)
        p = fmaf((float)hv[j], (float)tv[j], p);
#endif
    return p;
}

__device__ __forceinline__ void etype_accum(
    const _Float16* __restrict__ hr, const float* __restrict__ nrm,
    const unsigned short* __restrict__ slot, int m,
    half8 tvh, int grp, int l15,
    half2v* __restrict__ acc2, float& asum)
{
    half8 hv = {};
    float nr = 0.f;
    if (grp < m) {
        const int s = (int)slot[grp];
        hv = *(const half8*)(hr + (size_t)s * DIM + l15 * 8);
        nr = nrm[s];
    }
    for (int base = 0; base < m; base += 4) {
        half8 hvn = {};
        float nrn = 0.f;
        const int i2 = base + 4 + grp;
        if (i2 < m) {
            const int s2 = (int)slot[i2];
            hvn = *(const half8*)(hr + (size_t)s2 * DIM + l15 * 8);
            nrn = nrm[s2];
        }
        float p = dot16(hv, tvh);
        p += __shfl_xor(p, 1); p += __shfl_xor(p, 2);
        p += __shfl_xor(p, 4); p += __shfl_xor(p, 8);
        const float w = p * nr;
        const _Float16 wh = (_Float16)w;
        half2v wv; wv[0] = wh; wv[1] = wh;
        const H2x4 hp = __builtin_bit_cast(H2x4, hv);
        acc2[0] = hp.a * wv + acc2[0];
        acc2[1] = hp.b * wv + acc2[1];
        acc2[2] = hp.c * wv + acc2[2];
        acc2[3] = hp.d * wv + acc2[3];
        asum += p;
        hv = hvn; nr = nrn;
    }
}

__global__ __launch_bounds__(256) void aggregate_kernel(AggHalf a, int n)
{
    const int wave = threadIdx.x >> 6;
    const int lane = threadIdx.x & 63;
    const int grp = lane >> 4;
    const int l15 = lane & 15;

    const int part = blockIdx.x & (NPART - 1);
    const int idx = blockIdx.x >> 3;
    const int off = idx * 4 + wave;
    if (off >= PART_SZ) return;
    const int node = part * PART_SZ + off;
    if (node >= n) return;

    const half8 tvh = *(const half8*)(a.ht + (size_t)node * DIM + l15 * 8);
    const float inv_nt = a.invnt[node];

    half2v acc2A[4], acc2B[4];
    #pragma unroll
    for (int j = 0; j < 4; ++j) {
        acc2A[j][0] = (_Float16)0; acc2A[j][1] = (_Float16)0;
        acc2B[j][0] = (_Float16)0; acc2B[j][1] = (_Float16)0;
    }
    float aA = 0.f, aB = 0.f;

    const unsigned int oA = a.offA[node];
    const unsigned int oB = a.offB[node];
    const int degA = (int)(oA & 255u);
    const int degB = (int)(oB & 255u);

    etype_accum(a.hrA, a.nrmA, a.slotsA + (oA >> 8), degA, tvh, grp, l15, acc2A, aA);
    etype_accum(a.hrB, a.nrmB, a.slotsB + (oB >> 8), degB, tvh, grp, l15, acc2B, aB);

    // convert to f32, combine the 4 edge groups
    float accA[8], accB[8];
    #pragma unroll
    for (int j = 0; j < 4; ++j) {
        accA[2 * j + 0] = (float)acc2A[j][0];
        accA[2 * j + 1] = (float)acc2A[j][1];
        accB[2 * j + 0] = (float)acc2B[j][0];
        accB[2 * j + 1] = (float)acc2B[j][1];
    }
    #pragma unroll
    for (int j = 0; j < 8; ++j) {
        accA[j] += __shfl_xor(accA[j], 16); accA[j] += __shfl_xor(accA[j], 32);
        accB[j] += __shfl_xor(accB[j], 16); accB[j] += __shfl_xor(accB[j], 32);
    }
    aA += __shfl_xor(aA, 16); aA += __shfl_xor(aA, 32);
    aB += __shfl_xor(aB, 16); aB += __shfl_xor(aB, 32);

    const float maA = aA * inv_nt / fmaxf((float)degA, 1.0f);
    const float maB = aB * inv_nt / fmaxf((float)degB, 1.0f);
    const float mm = fmaxf(maA, maB);
    float wA = expf(maA - mm);
    float wB = expf(maB - mm);
    const float sc = inv_nt / (wA + wB);
    wA *= sc; wB *= sc;

    if (grp == 0) {
        float* orow = a.out + (size_t)node * DIM + l15 * 8;
        float4 o0, o1;
        o0.x = wA * accA[0] + wB * accB[0];
        o0.y = wA * accA[1] + wB * accB[1];
        o0.z = wA * accA[2] + wB * accB[2];
        o0.w = wA * accA[3] + wB * accB[3];
        o1.x = wA * accA[4] + wB * accB[4];
        o1.y = wA * accA[5] + wB * accB[5];
        o1.z = wA * accA[6] + wB * accB[6];
        o1.w = wA * accA[7] + wB * accB[7];
        *(float4*)(orow) = o0;
        *(float4*)(orow + 4) = o1;
    }
}

// ---------------------------------------------------------------------------
extern "C" void kernel_launch(void* const* d_in, const int* in_sizes, int n_in,
                              void* d_out, int out_size, void* d_ws, size_t ws_size,
                              hipStream_t stream)
{
    const float* feat_vul  = (const float*)d_in[0];
    const float* feat_code = (const float*)d_in[1];
    const int* src_e1 = (const int*)d_in[2];
    const int* dst_e1 = (const int*)d_in[3];
    const int* src_e2 = (const int*)d_in[4];
    const int* dst_e2 = (const int*)d_in[5];
    const int* src_e3 = (const int*)d_in[6];
    const int* dst_e3 = (const int*)d_in[7];
    const int* src_e4 = (const int*)d_in[8];
    const int* dst_e4 = (const int*)d_in[9];
    const float* W_e1 = (const float*)d_in[10];
    const float* W_e2 = (const float*)d_in[11];
    const float* W_e3 = (const float*)d_in[12];
    const float* W_e4 = (const float*)d_in[13];
    const float* W_vul  = (const float*)d_in[14];
    const float* b_vul  = (const float*)d_in[15];
    const float* W_code = (const float*)d_in[16];
    const float* b_code = (const float*)d_in[17];

    float* out = (float*)d_out;

    // ---- workspace (~103.2 MB, NO aliasing) ----
    const size_t HT = (size_t)NNODES * DIM * sizeof(_Float16);   // 12.8 MB
    const size_t SZ = (size_t)NNODES * sizeof(float);             // 200 KB
    char* ws = (char*)d_ws;
    _Float16* tbl[6];
    for (int i = 0; i < 6; ++i) tbl[i] = (_Float16*)(ws + i * HT);
    char* q = ws + 6 * HT;                                        // 76.8 MB
    float* aux[6];
    for (int i = 0; i < 6; ++i) { aux[i] = (float*)q; q += SZ; }  // +1.2
    unsigned int* region = (unsigned int*)q;
    q += (size_t)4 * ACH2 * 8 * RCAP * sizeof(unsigned int);      // +12.58
    unsigned char* cntH = (unsigned char*)q;
    q += (size_t)4 * CG * 8 * PART_SZ;                            // +3.2
    unsigned char* curRel = (unsigned char*)q;
    q += (size_t)4 * CG * 8 * PART_SZ;                            // +3.2
    unsigned int* offp = (unsigned int*)q;
    q += (size_t)4 * NNODES * sizeof(unsigned int);               // +0.8
    unsigned short* slots = (unsigned short*)q;
    q += (size_t)4 * ESLOTS * sizeof(unsigned short);             // +5.38
    int* cntA = (int*)q;   q += 4 * ACH2 * 8 * sizeof(int);       // 16 KB
    int* stripT = (int*)q; q += 4 * CG * 8 * NSTRIP * sizeof(int);// 16 KB

    // tables: 0=ht_vul 1=e1n 2=e2n 3=ht_code 4=e3n 5=e4n
    PartAArgs pa2;
    pa2.src[0] = src_e1; pa2.dst[0] = dst_e1;
    pa2.src[1] = src_e2; pa2.dst[1] = dst_e2;
    pa2.src[2] = src_e3; pa2.dst[2] = dst_e3;
    pa2.src[3] = src_e4; pa2.dst[3] = dst_e4;
    pa2.region = region; pa2.cntA = cntA;

    Proj2Args pj;
    pj.feat[0] = feat_vul;
    pj.W[0][0] = W_vul;  pj.W[0][1] = W_e3; pj.W[0][2] = W_e4;
    pj.bias[0] = b_vul;
    pj.out[0][0] = tbl[0]; pj.out[0][1] = tbl[4]; pj.out[0][2] = tbl[5];
    pj.aux[0][0] = aux[0]; pj.aux[0][1] = aux[4]; pj.aux[0][2] = aux[5];
    pj.feat[1] = feat_code;
    pj.W[1][0] = W_code; pj.W[1][1] = W_e1; pj.W[1][2] = W_e2;
    pj.bias[1] = b_code;
    pj.out[1][0] = tbl[3]; pj.out[1][1] = tbl[1]; pj.out[1][2] = tbl[2];
    pj.aux[1][0] = aux[3]; pj.aux[1][1] = aux[1]; pj.aux[1][2] = aux[2];

    SortArgs sa;
    sa.region = region; sa.cntA = cntA; sa.cntH = cntH; sa.stripT = stripT;
    sa.curRel = curRel; sa.offp = offp; sa.slots = slots;

    AggHalf h0 = { tbl[0], aux[0],
                   tbl[1], aux[1], offp + 0 * NNODES, slots + 0 * (size_t)ESLOTS,
                   tbl[2], aux[2], offp + 1 * NNODES, slots + 1 * (size_t)ESLOTS,
                   out };
    AggHalf h1 = { tbl[3], aux[3],
                   tbl[4], aux[4], offp + 2 * NNODES, slots + 2 * (size_t)ESLOTS,
                   tbl[5], aux[5], offp + 3 * NNODES, slots + 3 * (size_t)ESLOTS,
                   out + (size_t)NNODES * DIM };

    partA_kernel<<<dim3(ACH2, 4), 256, 0, stream>>>(pa2);
    proj2_kernel<<<dim3((NNODES + 127) / 128, 2, 3), 512, 0, stream>>>(pj, NNODES);
    hist_kernel<<<dim3(CG * 8, 4), 256, 0, stream>>>(sa);
    scan_kernel<<<dim3(NSTRIP * 8, 4), 256, 0, stream>>>(sa);
    place_kernel<<<dim3(CG * 8, 4), 256, 0, stream>>>(sa);

    const int aggX = NPART * ((PART_SZ + 3) / 4);           // 8 * 1563
    aggregate_kernel<<<aggX, 256, 0, stream>>>(h0, NNODES);
    aggregate_kernel<<<aggX, 256, 0, stream>>>(h1, NNODES);
}

// Round 20
// 237.269 us; speedup vs baseline: 1.0627x; 1.0627x over previous
//
#include <hip/hip_runtime.h>
#include <hip/hip_fp16.h>
#include <math.h>

#define NNODES 50000
#define DIM 128
#define NEDGES 640000
#define NPART 8         // one dst-partition per XCD
#define PART_SZ 6250    // 50000 / 8
#define ACH2 128        // partA chunks (640000/128 = 5000 exact)
#define APER2 5000
#define RCAP 768        // region cap: binom(5000,1/8) mean 625, sd 23 (+6sd)
#define CG 16           // chunk-groups for hist/place
#define CPG 8           // chunks per group (16*8 = 128)
#define WCAPP 84000     // per-partition slot window (mean 80000, sd 265, +15sd)
#define ESLOTS (NPART * WCAPP)   // 672000 slots per etype
#define STRIP 782       // scan strip size (8*782 = 6256 >= 6250)
#define NSTRIP 8

typedef _Float16 half8 __attribute__((ext_vector_type(8)));
typedef _Float16 half4v __attribute__((ext_vector_type(4)));
typedef _Float16 half2v __attribute__((ext_vector_type(2)));
typedef float f32x4 __attribute__((ext_vector_type(4)));
typedef int int4v __attribute__((ext_vector_type(4)));

struct H2x4 { half2v a, b, c, d; };

// ---------------------------------------------------------------------------
// partA: radix-compact edges by dst-partition. int4 nontemporal edge loads
// (5000 = 1250 exact int4s per chunk, aligned), 4 edges/lane/iter through
// the wave-aggregated ballot bucketing -> 4x fewer load round-trips.
// ---------------------------------------------------------------------------
struct PartAArgs {
    const int* src[4];
    const int* dst[4];
    unsigned int* region;   // [4][ACH2][8][RCAP]
    int* cntA;              // [4][ACH2][8]
};

__global__ __launch_bounds__(256) void partA_kernel(PartAArgs A)
{
    const int et = blockIdx.y;
    const int chunk = blockIdx.x;
    const int lane = threadIdx.x & 63;

    __shared__ int cur[8];
    if (threadIdx.x < 8) cur[threadIdx.x] = 0;
    __syncthreads();

    const int lo = chunk * APER2;
    const int4v* __restrict__ d4 = (const int4v*)(A.dst[et] + lo);
    const int4v* __restrict__ s4 = (const int4v*)(A.src[et] + lo);
    unsigned int* __restrict__ reg =
        A.region + (size_t)(et * ACH2 + chunk) * 8 * RCAP;

    const unsigned long long ltm = (1ULL << lane) - 1ULL;

    for (int it = 0; it < 5; ++it) {          // 5*256 = 1280 >= 1250 int4s
        const int i4 = it * 256 + threadIdx.x;
        const bool any = i4 < (APER2 / 4);    // 1250
        int4v dv = {}, sv = {};
        if (any) {
            dv = __builtin_nontemporal_load(d4 + i4);
            sv = __builtin_nontemporal_load(s4 + i4);
        }
        #pragma unroll
        for (int k = 0; k < 4; ++k) {
            const int d = dv[k];
            const int s = sv[k];
            const int pe = any ? (d / PART_SZ) : 8;
            const unsigned int pack =
                ((unsigned int)s << 13) | (unsigned int)(d - pe * PART_SZ);
            #pragma unroll
            for (int p = 0; p < 8; ++p) {
                const unsigned long long m = __ballot(pe == p);
                if (m == 0ULL) continue;
                const int leader = __builtin_ctzll(m);
                const int rank = __popcll(m & ltm);
                int base = 0;
                if (lane == leader) base = atomicAdd(&cur[p], __popcll(m));
                base = __shfl(base, leader);
                if (pe == p) {
                    const int pos = base + rank;
                    if (pos < RCAP) reg[p * RCAP + pos] = pack;
                }
            }
        }
    }
    __syncthreads();
    if (threadIdx.x < 8)
        A.cntA[(et * ACH2 + chunk) * 8 + threadIdx.x] = cur[threadIdx.x];
}

// ---------------------------------------------------------------------------
// proj2 (r18 proven form): 512 thr, 128 rows/block, 32 KB LDS single-W
// staging (3 serial W stages) -> 4 blocks/CU.
// ---------------------------------------------------------------------------
struct Proj2Args {
    const float* feat[2];
    const float* W[2][3];
    const float* bias[2];
    _Float16* out[2][3];
    float* aux[2][3];
};

__global__ __launch_bounds__(512) void proj2_kernel(Proj2Args args, int n)
{
    const int p = blockIdx.y;
    const float* __restrict__ feat = args.feat[p];

    __shared__ _Float16 wlds[DIM * DIM];    // 32 KB
    char* wb = (char*)wlds;

    const int wave = threadIdx.x >> 6;
    const int lane = threadIdx.x & 63;
    const int l15 = lane & 15;
    const int grp = lane >> 4;
    const int rbase = blockIdx.x * 128 + wave * 16;

    half8 afrag[4];
    const int arow = rbase + l15;
    const bool arow_ok = arow < n;
    #pragma unroll
    for (int kt = 0; kt < 4; ++kt) {
        float av[8];
        if (arow_ok) {
            const float* src = feat + (size_t)arow * DIM + kt * 32 + grp * 8;
            const float4 v0 = *(const float4*)(src);
            const float4 v1 = *(const float4*)(src + 4);
            av[0] = v0.x; av[1] = v0.y; av[2] = v0.z; av[3] = v0.w;
            av[4] = v1.x; av[5] = v1.y; av[6] = v1.z; av[7] = v1.w;
        } else {
            #pragma unroll
            for (int j = 0; j < 8; ++j) av[j] = 0.f;
        }
        #pragma unroll
        for (int j = 0; j < 8; ++j) afrag[kt][j] = (_Float16)av[j];
    }

    const int crow0 = rbase + grp * 4;

    for (int w3 = 0; w3 < 3; ++w3) {
        __syncthreads();    // previous w3's LDS reads done before overwrite
        {
            const float* __restrict__ W = args.W[p][w3];
            const int t = threadIdx.x;
            #pragma unroll
            for (int j = 0; j < 8; ++j) {
                const int idx4 = j * 512 + t;
                const float4 v = *(const float4*)(W + (size_t)idx4 * 4);
                const int o = idx4 >> 5;
                const int k = (idx4 * 4) & 127;
                half4v h;
                h[0] = (_Float16)v.x; h[1] = (_Float16)v.y;
                h[2] = (_Float16)v.z; h[3] = (_Float16)v.w;
                const int addr = (o * 256 + k * 2) ^ ((o & 7) << 4);
                *(half4v*)(wb + addr) = h;
            }
        }
        __syncthreads();

        _Float16* __restrict__ out = args.out[p][w3];
        float* __restrict__ aux = args.aux[p][w3];

        f32x4 accs[8];
        #pragma unroll
        for (int ct = 0; ct < 8; ++ct) {
            f32x4 acc = {0.f, 0.f, 0.f, 0.f};
            #pragma unroll
            for (int kt = 0; kt < 4; ++kt) {
                const int o = ct * 16 + l15;
                const int addr = (o * 256 + kt * 64 + grp * 16) ^ ((o & 7) << 4);
                const half8 b = *(const half8*)(wb + addr);
                acc = __builtin_amdgcn_mfma_f32_16x16x32_f16(afrag[kt], b, acc, 0, 0, 0);
            }
            if (w3 == 0) {
                const float bb = args.bias[p][ct * 16 + l15];
                acc[0] += bb; acc[1] += bb; acc[2] += bb; acc[3] += bb;
            }
            accs[ct] = acc;
        }

        float nsq[4] = {0.f, 0.f, 0.f, 0.f};
        #pragma unroll
        for (int ct = 0; ct < 8; ++ct) {
            #pragma unroll
            for (int i = 0; i < 4; ++i)
                nsq[i] = fmaf(accs[ct][i], accs[ct][i], nsq[i]);
        }
        #pragma unroll
        for (int i = 0; i < 4; ++i) {
            float v = nsq[i];
            v += __shfl_xor(v, 1); v += __shfl_xor(v, 2);
            v += __shfl_xor(v, 4); v += __shfl_xor(v, 8);
            nsq[i] = fmaxf(v, 1e-30f);
        }

        if (w3 == 0) {
            #pragma unroll
            for (int ct = 0; ct < 8; ++ct)
                #pragma unroll
                for (int i = 0; i < 4; ++i) {
                    const int row = crow0 + i;
                    if (row < n)
                        out[(size_t)row * DIM + ct * 16 + l15] = (_Float16)accs[ct][i];
                }
            if (l15 == 0) {
                #pragma unroll
                for (int i = 0; i < 4; ++i) {
                    const int row = crow0 + i;
                    if (row < n) aux[row] = 1.0f / sqrtf(nsq[i]);
                }
            }
        } else {
            float rn[4];
            #pragma unroll
            for (int i = 0; i < 4; ++i) rn[i] = 1.0f / sqrtf(nsq[i]);
            #pragma unroll
            for (int ct = 0; ct < 8; ++ct)
                #pragma unroll
                for (int i = 0; i < 4; ++i) {
                    const int row = crow0 + i;
                    if (row < n)
                        out[(size_t)row * DIM + ct * 16 + l15] =
                            (_Float16)(accs[ct][i] * rn[i]);
                }
            if (l15 == 0) {
                #pragma unroll
                for (int i = 0; i < 4; ++i) {
                    const int row = crow0 + i;
                    if (row < n) aux[row] = sqrtf(nsq[i]);
                }
            }
        }
    }
}

// ---------------------------------------------------------------------------
// sort chain (u8 metadata): hist -> scan -> place
// ---------------------------------------------------------------------------
struct SortArgs {
    const unsigned int* region;
    const int* cntA;
    unsigned char* cntH;    // [4][CG][8][PART_SZ]
    int* stripT;            // [4][CG][8][NSTRIP]
    unsigned char* curRel;  // [4][CG][8][PART_SZ]
    unsigned int* offp;     // [4][NNODES]  (abs_start<<8)|deg
    unsigned short* slots;  // [4][ESLOTS]
};

__global__ __launch_bounds__(256) void hist_kernel(SortArgs A)
{
    const int et = blockIdx.y;
    const int cg = blockIdx.x >> 3;
    const int part = blockIdx.x & 7;
    const int tid = threadIdx.x;

    __shared__ int cnt[PART_SZ];          // 25 KB
    for (int i = tid; i < PART_SZ; i += 256) cnt[i] = 0;
    __syncthreads();

    #pragma unroll
    for (int k = 0; k < CPG; ++k) {
        const int c = cg * CPG + k;
        int m = A.cntA[(et * ACH2 + c) * 8 + part];
        if (m > RCAP) m = RCAP;
        const unsigned int* __restrict__ r =
            A.region + ((size_t)(et * ACH2 + c) * 8 + part) * RCAP;
        for (int i = tid; i < m; i += 256)
            atomicAdd(&cnt[r[i] & 8191u], 1);
    }
    __syncthreads();

    unsigned char* __restrict__ out =
        A.cntH + ((size_t)(et * CG + cg) * 8 + part) * PART_SZ;
    for (int i = tid; i < PART_SZ; i += 256)
        out[i] = (unsigned char)(cnt[i] < 255 ? cnt[i] : 255);

    if (tid < 64) {
        for (int s = 0; s < NSTRIP; ++s) {
            const int lo = s * STRIP;
            const int sz = (lo + STRIP < PART_SZ) ? STRIP : (PART_SZ - lo);
            int partial = 0;
            for (int i = tid; i < sz; i += 64) partial += cnt[lo + i];
            partial += __shfl_xor(partial, 1);
            partial += __shfl_xor(partial, 2);
            partial += __shfl_xor(partial, 4);
            partial += __shfl_xor(partial, 8);
            partial += __shfl_xor(partial, 16);
            partial += __shfl_xor(partial, 32);
            if (tid == 0)
                A.stripT[((et * CG + cg) * 8 + part) * NSTRIP + s] = partial;
        }
    }
}

__global__ __launch_bounds__(256) void scan_kernel(SortArgs A)
{
    const int et = blockIdx.y;
    const int part = blockIdx.x & 7;
    const int strip = blockIdx.x >> 3;
    const int t = threadIdx.x;
    const int nlo = strip * STRIP;
    const int nsz = (nlo + STRIP < PART_SZ) ? STRIP : (PART_SZ - nlo);

    __shared__ int tile[CG][STRIP];       // 50 KB
    __shared__ int red[2][256];
    __shared__ int sbase;

    const size_t base0 = ((size_t)(et * CG) * 8 + part) * PART_SZ;
    const size_t cgs = (size_t)8 * PART_SZ;

    for (int cg = 0; cg < CG; ++cg)
        for (int i = t; i < nsz; i += 256)
            tile[cg][i] = (int)A.cntH[base0 + cg * cgs + nlo + i];

    {
        int partial = 0;
        for (int idx = t; idx < CG * NSTRIP; idx += 256) {
            const int cg = idx >> 3;
            const int s = idx & 7;
            if (s < strip)
                partial += A.stripT[((et * CG + cg) * 8 + part) * NSTRIP + s];
        }
        red[0][t] = partial;
        __syncthreads();
        for (int d = 128; d > 0; d >>= 1) {
            if (t < d) red[0][t] += red[0][t + d];
            __syncthreads();
        }
        if (t == 0) sbase = red[0][0];
        __syncthreads();
    }

    int s = 0;
    #pragma unroll
    for (int k = 0; k < 4; ++k) {
        const int idx = t * 4 + k;
        if (idx < nsz) {
            int deg = 0;
            for (int cg = 0; cg < CG; ++cg) deg += tile[cg][idx];
            s += deg;
        }
    }
    red[0][t] = s;
    __syncthreads();
    int pp = 0;
    for (int d = 1; d < 256; d <<= 1) {
        int v = red[pp][t];
        if (t >= d) v += red[pp][t - d];
        red[pp ^ 1][t] = v;
        pp ^= 1;
        __syncthreads();
    }
    int run = part * WCAPP + sbase + (t == 0 ? 0 : red[pp][t - 1]);

    unsigned int* __restrict__ offe = A.offp + et * NNODES + part * PART_SZ + nlo;
    #pragma unroll
    for (int k = 0; k < 4; ++k) {
        const int idx = t * 4 + k;
        if (idx < nsz) {
            const int nb = run;
            int b = run;
            for (int cg = 0; cg < CG; ++cg) {
                A.curRel[base0 + cg * cgs + nlo + idx] = (unsigned char)(b - nb);
                b += tile[cg][idx];
            }
            const int deg = b - nb;
            offe[idx] = ((unsigned int)nb << 8) |
                        (unsigned int)(deg < 255 ? deg : 255);
            run = b;
        }
    }
}

__global__ __launch_bounds__(256) void place_kernel(SortArgs A)
{
    const int et = blockIdx.y;
    const int cg = blockIdx.x >> 3;
    const int part = blockIdx.x & 7;
    const int tid = threadIdx.x;

    __shared__ int cur[PART_SZ];          // 25 KB
    const unsigned char* __restrict__ crel =
        A.curRel + ((size_t)(et * CG + cg) * 8 + part) * PART_SZ;
    const unsigned int* __restrict__ offe =
        A.offp + et * NNODES + part * PART_SZ;
    for (int i = tid; i < PART_SZ; i += 256)
        cur[i] = (int)(offe[i] >> 8) + (int)crel[i];
    __syncthreads();

    unsigned short* __restrict__ sl = A.slots + (size_t)et * ESLOTS;

    #pragma unroll
    for (int k = 0; k < CPG; ++k) {
        const int c = cg * CPG + k;
        int m = A.cntA[(et * ACH2 + c) * 8 + part];
        if (m > RCAP) m = RCAP;
        const unsigned int* __restrict__ r =
            A.region + ((size_t)(et * ACH2 + c) * 8 + part) * RCAP;
        for (int i = tid; i < m; i += 256) {
            const unsigned int pk = r[i];
            const int dl = (int)(pk & 8191u);
            const int pos = atomicAdd(&cur[dl], 1);
            if (pos < ESLOTS) sl[pos] = (unsigned short)(pk >> 13);
        }
    }
}

// ---------------------------------------------------------------------------
// aggregate (r15/r18 proven form, grid.y=2): wave per dst node, 16
// lanes/edge, fdot2 dot, f16 packed accumulate, 1-deep prefetch, XCD-aligned.
// ---------------------------------------------------------------------------
struct AggHalf {
    const _Float16* ht; const float* invnt;
    const _Float16* hrA; const float* nrmA;
    const unsigned int* offA; const unsigned short* slotsA;
    const _Float16* hrB; const float* nrmB;
    const unsigned int* offB; const unsigned short* slotsB;
    float* out;
};
struct AggArgs { AggHalf h[2]; };

__device__ __forceinline__ float dot16(half8 hv, half8 tv)
{
    float p = 0.f;
#if __has_builtin(__builtin_amdgcn_fdot2)
    const H2x4 hu = __builtin_bit_cast(H2x4, hv);
    const H2x4 tu = __builtin_bit_cast(H2x4, tv);
    p = __builtin_amdgcn_fdot2(hu.a, tu.a, p, false);
    p = __builtin_amdgcn_fdot2(hu.b, tu.b, p, false);
    p = __builtin_amdgcn_fdot2(hu.c, tu.c, p, false);
    p = __builtin_amdgcn_fdot2(hu.d, tu.d, p, false);
#else
    #pragma unroll
    for (int j = 0; j < 8; ++j)
        p = fmaf((float)hv[j], (float)tv[j], p);
#endif
    return p;
}

__device__ __forceinline__ void etype_accum(
    const _Float16* __restrict__ hr, const float* __restrict__ nrm,
    const unsigned short* __restrict__ slot, int m,
    half8 tvh, int grp, int l15,
    half2v* __restrict__ acc2, float& asum)
{
    half8 hv = {};
    float nr = 0.f;
    if (grp < m) {
        const int s = (int)slot[grp];
        hv = *(const half8*)(hr + (size_t)s * DIM + l15 * 8);
        nr = nrm[s];
    }
    for (int base = 0; base < m; base += 4) {
        half8 hvn = {};
        float nrn = 0.f;
        const int i2 = base + 4 + grp;
        if (i2 < m) {
            const int s2 = (int)slot[i2];
            hvn = *(const half8*)(hr + (size_t)s2 * DIM + l15 * 8);
            nrn = nrm[s2];
        }
        float p = dot16(hv, tvh);
        p += __shfl_xor(p, 1); p += __shfl_xor(p, 2);
        p += __shfl_xor(p, 4); p += __shfl_xor(p, 8);
        const float w = p * nr;
        const _Float16 wh = (_Float16)w;
        half2v wv; wv[0] = wh; wv[1] = wh;
        const H2x4 hp = __builtin_bit_cast(H2x4, hv);
        acc2[0] = hp.a * wv + acc2[0];
        acc2[1] = hp.b * wv + acc2[1];
        acc2[2] = hp.c * wv + acc2[2];
        acc2[3] = hp.d * wv + acc2[3];
        asum += p;
        hv = hvn; nr = nrn;
    }
}

__global__ __launch_bounds__(256, 8) void aggregate_kernel(AggArgs A, int n)
{
    const AggHalf& a = A.h[blockIdx.y];
    const int wave = threadIdx.x >> 6;
    const int lane = threadIdx.x & 63;
    const int grp = lane >> 4;
    const int l15 = lane & 15;

    const int part = blockIdx.x & (NPART - 1);
    const int idx = blockIdx.x >> 3;
    const int off = idx * 4 + wave;
    if (off >= PART_SZ) return;
    const int node = part * PART_SZ + off;
    if (node >= n) return;

    const half8 tvh = *(const half8*)(a.ht + (size_t)node * DIM + l15 * 8);
    const float inv_nt = a.invnt[node];

    half2v acc2A[4], acc2B[4];
    #pragma unroll
    for (int j = 0; j < 4; ++j) {
        acc2A[j][0] = (_Float16)0; acc2A[j][1] = (_Float16)0;
        acc2B[j][0] = (_Float16)0; acc2B[j][1] = (_Float16)0;
    }
    float aA = 0.f, aB = 0.f;

    const unsigned int oA = a.offA[node];
    const unsigned int oB = a.offB[node];
    const int degA = (int)(oA & 255u);
    const int degB = (int)(oB & 255u);

    etype_accum(a.hrA, a.nrmA, a.slotsA + (oA >> 8), degA, tvh, grp, l15, acc2A, aA);
    etype_accum(a.hrB, a.nrmB, a.slotsB + (oB >> 8), degB, tvh, grp, l15, acc2B, aB);

    // convert to f32, combine the 4 edge groups
    float accA[8], accB[8];
    #pragma unroll
    for (int j = 0; j < 4; ++j) {
        accA[2 * j + 0] = (float)acc2A[j][0];
        accA[2 * j + 1] = (float)acc2A[j][1];
        accB[2 * j + 0] = (float)acc2B[j][0];
        accB[2 * j + 1] = (float)acc2B[j][1];
    }
    #pragma unroll
    for (int j = 0; j < 8; ++j) {
        accA[j] += __shfl_xor(accA[j], 16); accA[j] += __shfl_xor(accA[j], 32);
        accB[j] += __shfl_xor(accB[j], 16); accB[j] += __shfl_xor(accB[j], 32);
    }
    aA += __shfl_xor(aA, 16); aA += __shfl_xor(aA, 32);
    aB += __shfl_xor(aB, 16); aB += __shfl_xor(aB, 32);

    const float maA = aA * inv_nt / fmaxf((float)degA, 1.0f);
    const float maB = aB * inv_nt / fmaxf((float)degB, 1.0f);
    const float mm = fmaxf(maA, maB);
    float wA = expf(maA - mm);
    float wB = expf(maB - mm);
    const float sc = inv_nt / (wA + wB);
    wA *= sc; wB *= sc;

    if (grp == 0) {
        float* orow = a.out + (size_t)node * DIM + l15 * 8;
        float4 o0, o1;
        o0.x = wA * accA[0] + wB * accB[0];
        o0.y = wA * accA[1] + wB * accB[1];
        o0.z = wA * accA[2] + wB * accB[2];
        o0.w = wA * accA[3] + wB * accB[3];
        o1.x = wA * accA[4] + wB * accB[4];
        o1.y = wA * accA[5] + wB * accB[5];
        o1.z = wA * accA[6] + wB * accB[6];
        o1.w = wA * accA[7] + wB * accB[7];
        *(float4*)(orow) = o0;
        *(float4*)(orow + 4) = o1;
    }
}

// ---------------------------------------------------------------------------
extern "C" void kernel_launch(void* const* d_in, const int* in_sizes, int n_in,
                              void* d_out, int out_size, void* d_ws, size_t ws_size,
                              hipStream_t stream)
{
    const float* feat_vul  = (const float*)d_in[0];
    const float* feat_code = (const float*)d_in[1];
    const int* src_e1 = (const int*)d_in[2];
    const int* dst_e1 = (const int*)d_in[3];
    const int* src_e2 = (const int*)d_in[4];
    const int* dst_e2 = (const int*)d_in[5];
    const int* src_e3 = (const int*)d_in[6];
    const int* dst_e3 = (const int*)d_in[7];
    const int* src_e4 = (const int*)d_in[8];
    const int* dst_e4 = (const int*)d_in[9];
    const float* W_e1 = (const float*)d_in[10];
    const float* W_e2 = (const float*)d_in[11];
    const float* W_e3 = (const float*)d_in[12];
    const float* W_e4 = (const float*)d_in[13];
    const float* W_vul  = (const float*)d_in[14];
    const float* b_vul  = (const float*)d_in[15];
    const float* W_code = (const float*)d_in[16];
    const float* b_code = (const float*)d_in[17];

    float* out = (float*)d_out;

    // ---- workspace (~103.2 MB, NO aliasing) ----
    const size_t HT = (size_t)NNODES * DIM * sizeof(_Float16);   // 12.8 MB
    const size_t SZ = (size_t)NNODES * sizeof(float);             // 200 KB
    char* ws = (char*)d_ws;
    _Float16* tbl[6];
    for (int i = 0; i < 6; ++i) tbl[i] = (_Float16*)(ws + i * HT);
    char* q = ws + 6 * HT;                                        // 76.8 MB
    float* aux[6];
    for (int i = 0; i < 6; ++i) { aux[i] = (float*)q; q += SZ; }  // +1.2
    unsigned int* region = (unsigned int*)q;
    q += (size_t)4 * ACH2 * 8 * RCAP * sizeof(unsigned int);      // +12.58
    unsigned char* cntH = (unsigned char*)q;
    q += (size_t)4 * CG * 8 * PART_SZ;                            // +3.2
    unsigned char* curRel = (unsigned char*)q;
    q += (size_t)4 * CG * 8 * PART_SZ;                            // +3.2
    unsigned int* offp = (unsigned int*)q;
    q += (size_t)4 * NNODES * sizeof(unsigned int);               // +0.8
    unsigned short* slots = (unsigned short*)q;
    q += (size_t)4 * ESLOTS * sizeof(unsigned short);             // +5.38
    int* cntA = (int*)q;   q += 4 * ACH2 * 8 * sizeof(int);       // 16 KB
    int* stripT = (int*)q; q += 4 * CG * 8 * NSTRIP * sizeof(int);// 16 KB

    // tables: 0=ht_vul 1=e1n 2=e2n 3=ht_code 4=e3n 5=e4n
    PartAArgs pa2;
    pa2.src[0] = src_e1; pa2.dst[0] = dst_e1;
    pa2.src[1] = src_e2; pa2.dst[1] = dst_e2;
    pa2.src[2] = src_e3; pa2.dst[2] = dst_e3;
    pa2.src[3] = src_e4; pa2.dst[3] = dst_e4;
    pa2.region = region; pa2.cntA = cntA;

    Proj2Args pj;
    pj.feat[0] = feat_vul;
    pj.W[0][0] = W_vul;  pj.W[0][1] = W_e3; pj.W[0][2] = W_e4;
    pj.bias[0] = b_vul;
    pj.out[0][0] = tbl[0]; pj.out[0][1] = tbl[4]; pj.out[0][2] = tbl[5];
    pj.aux[0][0] = aux[0]; pj.aux[0][1] = aux[4]; pj.aux[0][2] = aux[5];
    pj.feat[1] = feat_code;
    pj.W[1][0] = W_code; pj.W[1][1] = W_e1; pj.W[1][2] = W_e2;
    pj.bias[1] = b_code;
    pj.out[1][0] = tbl[3]; pj.out[1][1] = tbl[1]; pj.out[1][2] = tbl[2];
    pj.aux[1][0] = aux[3]; pj.aux[1][1] = aux[1]; pj.aux[1][2] = aux[2];

    SortArgs sa;
    sa.region = region; sa.cntA = cntA; sa.cntH = cntH; sa.stripT = stripT;
    sa.curRel = curRel; sa.offp = offp; sa.slots = slots;

    AggArgs aa;
    aa.h[0] = { tbl[0], aux[0],
                tbl[1], aux[1], offp + 0 * NNODES, slots + 0 * (size_t)ESLOTS,
                tbl[2], aux[2], offp + 1 * NNODES, slots + 1 * (size_t)ESLOTS,
                out };
    aa.h[1] = { tbl[3], aux[3],
                tbl[4], aux[4], offp + 2 * NNODES, slots + 2 * (size_t)ESLOTS,
                tbl[5], aux[5], offp + 3 * NNODES, slots + 3 * (size_t)ESLOTS,
                out + (size_t)NNODES * DIM };

    partA_kernel<<<dim3(ACH2, 4), 256, 0, stream>>>(pa2);
    proj2_kernel<<<dim3((NNODES + 127) / 128, 2), 512, 0, stream>>>(pj, NNODES);
    hist_kernel<<<dim3(CG * 8, 4), 256, 0, stream>>>(sa);
    scan_kernel<<<dim3(NSTRIP * 8, 4), 256, 0, stream>>>(sa);
    place_kernel<<<dim3(CG * 8, 4), 256, 0, stream>>>(sa);

    const int aggX = NPART * ((PART_SZ + 3) / 4);           // 8 * 1563
    aggregate_kernel<<<dim3(aggX, 2), 256, 0, stream>>>(aa, NNODES);
}